// Round 1
// baseline (25.287 us; speedup 1.0000x reference)
//
#include <hip/hip_runtime.h>

#define BLOCK 256
#define NCOL 2048

__device__ __forceinline__ float waveReduceMax(float v) {
#pragma unroll
    for (int o = 32; o > 0; o >>= 1) v = fmaxf(v, __shfl_xor(v, o, 64));
    return v;
}
__device__ __forceinline__ float waveReduceSum(float v) {
#pragma unroll
    for (int o = 32; o > 0; o >>= 1) v += __shfl_xor(v, o, 64);
    return v;
}

__global__ __launch_bounds__(BLOCK) void interval_softmax_kernel(
    const float* __restrict__ L, const float* __restrict__ U,
    float* __restrict__ lo, float* __restrict__ up)
{
    const int row  = blockIdx.x;
    const int tid  = threadIdx.x;
    const int wave = tid >> 6;
    const int lane = tid & 63;

    const float4* L4 = reinterpret_cast<const float4*>(L) + (size_t)row * (NCOL / 4);
    const float4* U4 = reinterpret_cast<const float4*>(U) + (size_t)row * (NCOL / 4);

    // Each thread owns 8 l-elements and 8 u-elements (2 float4 each),
    // coalesced: lane i reads float4 index i, then i+BLOCK.
    float4 a0 = L4[tid];
    float4 a1 = L4[tid + BLOCK];
    float4 b0 = U4[tid];
    float4 b1 = U4[tid + BLOCK];

    // ---- Phase 1: row max over both l and u ----
    float m = fmaxf(fmaxf(fmaxf(a0.x, a0.y), fmaxf(a0.z, a0.w)),
                    fmaxf(fmaxf(a1.x, a1.y), fmaxf(a1.z, a1.w)));
    m = fmaxf(m, fmaxf(fmaxf(fmaxf(b0.x, b0.y), fmaxf(b0.z, b0.w)),
                       fmaxf(fmaxf(b1.x, b1.y), fmaxf(b1.z, b1.w))));
    m = waveReduceMax(m);

    __shared__ float smax[4];
    __shared__ float ssl[4];
    __shared__ float ssu[4];
    if (lane == 0) smax[wave] = m;
    __syncthreads();
    m = fmaxf(fmaxf(smax[0], smax[1]), fmaxf(smax[2], smax[3]));

    // ---- Phase 2: exponentials + row sums (both sums in one reduction pass) ----
    float4 el0, el1, eu0, eu1;
    el0.x = __expf(a0.x - m); el0.y = __expf(a0.y - m);
    el0.z = __expf(a0.z - m); el0.w = __expf(a0.w - m);
    el1.x = __expf(a1.x - m); el1.y = __expf(a1.y - m);
    el1.z = __expf(a1.z - m); el1.w = __expf(a1.w - m);
    eu0.x = __expf(b0.x - m); eu0.y = __expf(b0.y - m);
    eu0.z = __expf(b0.z - m); eu0.w = __expf(b0.w - m);
    eu1.x = __expf(b1.x - m); eu1.y = __expf(b1.y - m);
    eu1.z = __expf(b1.z - m); eu1.w = __expf(b1.w - m);

    float sl = (el0.x + el0.y) + (el0.z + el0.w) + (el1.x + el1.y) + (el1.z + el1.w);
    float su = (eu0.x + eu0.y) + (eu0.z + eu0.w) + (eu1.x + eu1.y) + (eu1.z + eu1.w);
    sl = waveReduceSum(sl);
    su = waveReduceSum(su);
    if (lane == 0) { ssl[wave] = sl; ssu[wave] = su; }
    __syncthreads();
    sl = (ssl[0] + ssl[1]) + (ssl[2] + ssl[3]);
    su = (ssu[0] + ssu[1]) + (ssu[2] + ssu[3]);

    // ---- Phase 3: ratios + coalesced float4 stores ----
    // lower = e_l / (e_l + (S_u - e_u));  upper = e_u / (e_u + (S_l - e_l))
    float4 o0, o1;
    o0.x = __fdividef(el0.x, el0.x + (su - eu0.x));
    o0.y = __fdividef(el0.y, el0.y + (su - eu0.y));
    o0.z = __fdividef(el0.z, el0.z + (su - eu0.z));
    o0.w = __fdividef(el0.w, el0.w + (su - eu0.w));
    o1.x = __fdividef(el1.x, el1.x + (su - eu1.x));
    o1.y = __fdividef(el1.y, el1.y + (su - eu1.y));
    o1.z = __fdividef(el1.z, el1.z + (su - eu1.z));
    o1.w = __fdividef(el1.w, el1.w + (su - eu1.w));

    float4* lo4 = reinterpret_cast<float4*>(lo) + (size_t)row * (NCOL / 4);
    lo4[tid]         = o0;
    lo4[tid + BLOCK] = o1;

    float4 p0, p1;
    p0.x = __fdividef(eu0.x, eu0.x + (sl - el0.x));
    p0.y = __fdividef(eu0.y, eu0.y + (sl - el0.y));
    p0.z = __fdividef(eu0.z, eu0.z + (sl - el0.z));
    p0.w = __fdividef(eu0.w, eu0.w + (sl - el0.w));
    p1.x = __fdividef(eu1.x, eu1.x + (sl - el1.x));
    p1.y = __fdividef(eu1.y, eu1.y + (sl - el1.y));
    p1.z = __fdividef(eu1.z, eu1.z + (sl - el1.z));
    p1.w = __fdividef(eu1.w, eu1.w + (sl - el1.w));

    float4* up4 = reinterpret_cast<float4*>(up) + (size_t)row * (NCOL / 4);
    up4[tid]         = p0;
    up4[tid + BLOCK] = p1;
}

extern "C" void kernel_launch(void* const* d_in, const int* in_sizes, int n_in,
                              void* d_out, int out_size, void* d_ws, size_t ws_size,
                              hipStream_t stream) {
    const float* L = (const float*)d_in[0];
    const float* U = (const float*)d_in[1];
    const int rows = in_sizes[0] / NCOL;  // B = 4096
    float* lo = (float*)d_out;
    float* up = lo + (size_t)rows * NCOL;
    interval_softmax_kernel<<<rows, BLOCK, 0, stream>>>(L, U, lo, up);
}

// Round 3
// 25.253 us; speedup vs baseline: 1.0014x; 1.0014x over previous
//
#include <hip/hip_runtime.h>

#define BLOCK 256
#define NCOL 2048

typedef float f32x4 __attribute__((ext_vector_type(4)));

__device__ __forceinline__ float waveReduceMax(float v) {
#pragma unroll
    for (int o = 32; o > 0; o >>= 1) v = fmaxf(v, __shfl_xor(v, o, 64));
    return v;
}
__device__ __forceinline__ float waveReduceSum(float v) {
#pragma unroll
    for (int o = 32; o > 0; o >>= 1) v += __shfl_xor(v, o, 64);
    return v;
}

__global__ __launch_bounds__(BLOCK) void interval_softmax_kernel(
    const float* __restrict__ L, const float* __restrict__ U,
    float* __restrict__ lo, float* __restrict__ up)
{
    const int row  = blockIdx.x;
    const int tid  = threadIdx.x;
    const int wave = tid >> 6;
    const int lane = tid & 63;

    const f32x4* L4 = reinterpret_cast<const f32x4*>(L) + (size_t)row * (NCOL / 4);
    const f32x4* U4 = reinterpret_cast<const f32x4*>(U) + (size_t)row * (NCOL / 4);

    // Each thread owns 8 l-elements and 8 u-elements (2 float4 each),
    // coalesced: lane i reads vec4 index i, then i+BLOCK.
    f32x4 a0 = L4[tid];
    f32x4 a1 = L4[tid + BLOCK];
    f32x4 b0 = U4[tid];
    f32x4 b1 = U4[tid + BLOCK];

    // ---- Phase 1: row max over both l and u ----
    float m = fmaxf(fmaxf(fmaxf(a0.x, a0.y), fmaxf(a0.z, a0.w)),
                    fmaxf(fmaxf(a1.x, a1.y), fmaxf(a1.z, a1.w)));
    m = fmaxf(m, fmaxf(fmaxf(fmaxf(b0.x, b0.y), fmaxf(b0.z, b0.w)),
                       fmaxf(fmaxf(b1.x, b1.y), fmaxf(b1.z, b1.w))));
    m = waveReduceMax(m);

    __shared__ float smax[4];
    __shared__ float ssl[4];
    __shared__ float ssu[4];
    if (lane == 0) smax[wave] = m;
    __syncthreads();
    m = fmaxf(fmaxf(smax[0], smax[1]), fmaxf(smax[2], smax[3]));

    // ---- Phase 2: exponentials + row sums (both sums in one reduction pass) ----
    f32x4 el0, el1, eu0, eu1;
    el0.x = __expf(a0.x - m); el0.y = __expf(a0.y - m);
    el0.z = __expf(a0.z - m); el0.w = __expf(a0.w - m);
    el1.x = __expf(a1.x - m); el1.y = __expf(a1.y - m);
    el1.z = __expf(a1.z - m); el1.w = __expf(a1.w - m);
    eu0.x = __expf(b0.x - m); eu0.y = __expf(b0.y - m);
    eu0.z = __expf(b0.z - m); eu0.w = __expf(b0.w - m);
    eu1.x = __expf(b1.x - m); eu1.y = __expf(b1.y - m);
    eu1.z = __expf(b1.z - m); eu1.w = __expf(b1.w - m);

    float sl = (el0.x + el0.y) + (el0.z + el0.w) + (el1.x + el1.y) + (el1.z + el1.w);
    float su = (eu0.x + eu0.y) + (eu0.z + eu0.w) + (eu1.x + eu1.y) + (eu1.z + eu1.w);
    sl = waveReduceSum(sl);
    su = waveReduceSum(su);
    if (lane == 0) { ssl[wave] = sl; ssu[wave] = su; }
    __syncthreads();
    sl = (ssl[0] + ssl[1]) + (ssl[2] + ssl[3]);
    su = (ssu[0] + ssu[1]) + (ssu[2] + ssu[3]);

    // ---- Phase 3: ratios + coalesced NON-TEMPORAL vec4 stores ----
    // Outputs are write-once, never re-read: stream them past the caches so
    // the input arrays stay resident in Infinity Cache across graph replays.
    f32x4 o0, o1;
    o0.x = __fdividef(el0.x, el0.x + (su - eu0.x));
    o0.y = __fdividef(el0.y, el0.y + (su - eu0.y));
    o0.z = __fdividef(el0.z, el0.z + (su - eu0.z));
    o0.w = __fdividef(el0.w, el0.w + (su - eu0.w));
    o1.x = __fdividef(el1.x, el1.x + (su - eu1.x));
    o1.y = __fdividef(el1.y, el1.y + (su - eu1.y));
    o1.z = __fdividef(el1.z, el1.z + (su - eu1.z));
    o1.w = __fdividef(el1.w, el1.w + (su - eu1.w));

    f32x4* lo4 = reinterpret_cast<f32x4*>(lo) + (size_t)row * (NCOL / 4);
    __builtin_nontemporal_store(o0, &lo4[tid]);
    __builtin_nontemporal_store(o1, &lo4[tid + BLOCK]);

    f32x4 p0, p1;
    p0.x = __fdividef(eu0.x, eu0.x + (sl - el0.x));
    p0.y = __fdividef(eu0.y, eu0.y + (sl - el0.y));
    p0.z = __fdividef(eu0.z, eu0.z + (sl - el0.z));
    p0.w = __fdividef(eu0.w, eu0.w + (sl - el0.w));
    p1.x = __fdividef(eu1.x, eu1.x + (sl - el1.x));
    p1.y = __fdividef(eu1.y, eu1.y + (sl - el1.y));
    p1.z = __fdividef(eu1.z, eu1.z + (sl - el1.z));
    p1.w = __fdividef(eu1.w, eu1.w + (sl - el1.w));

    f32x4* up4 = reinterpret_cast<f32x4*>(up) + (size_t)row * (NCOL / 4);
    __builtin_nontemporal_store(p0, &up4[tid]);
    __builtin_nontemporal_store(p1, &up4[tid + BLOCK]);
}

extern "C" void kernel_launch(void* const* d_in, const int* in_sizes, int n_in,
                              void* d_out, int out_size, void* d_ws, size_t ws_size,
                              hipStream_t stream) {
    const float* L = (const float*)d_in[0];
    const float* U = (const float*)d_in[1];
    const int rows = in_sizes[0] / NCOL;  // B = 4096
    float* lo = (float*)d_out;
    float* up = lo + (size_t)rows * NCOL;
    interval_softmax_kernel<<<rows, BLOCK, 0, stream>>>(L, U, lo, up);
}